// Round 2
// baseline (309.741 us; speedup 1.0000x reference)
//
#include <hip/hip_runtime.h>

// GRU: B=2048, T=1024, I=1, H=20, fused with output projection.
// One wave per sequence (2048 waves = 2 waves/SIMD chip-wide).
//   lanes  0..19 : r-gate rows of W_hh   (weights pre-scaled by log2e)
//   lanes 20..39 : z-gate rows           (pre-scaled by log2e)
//   lanes 40..59 : n-gate rows           (pre-scaled by 2*log2e); own h[j]
//   lane  60     : W_out row (unscaled)  -> y from the same shared dot
//   lanes 61..63 : zero weights (idle)
// h-broadcast: 20x v_readlane into SGPRs (no LDS on the critical chain).
// r,z -> n-lane transport: 2x ds_bpermute (__shfl), latencies overlap.
// y: lane 60 ds_writes into a 64-slot LDS ring; coalesced flush every 64 steps.

#define LOG2E 1.44269504088896340736f

static __device__ __forceinline__ float fast_rcp(float x) {
    return __builtin_amdgcn_rcpf(x);
}
static __device__ __forceinline__ float fast_exp2(float x) {
    float r;
    asm("v_exp_f32 %0, %1" : "=v"(r) : "v"(x));
    return r;
}
static __device__ __forceinline__ float lane_bcast(float v, int srclane) {
    return __int_as_float(__builtin_amdgcn_readlane(__float_as_int(v), srclane));
}

__global__ __launch_bounds__(64) void gru_fused(
    const float* __restrict__ X,     // [B, T, 1]
    const float* __restrict__ H0,    // [1, B, 20]
    const float* __restrict__ Wih,   // [60, 1]
    const float* __restrict__ Whh,   // [60, 20]
    const float* __restrict__ Bih,   // [60]
    const float* __restrict__ Bhh,   // [60]
    const float* __restrict__ Wout,  // [1, 20]
    const float* __restrict__ Bout,  // [1]
    float* __restrict__ Y,           // [B*T]
    float* __restrict__ Hlast)       // [B, 20]
{
    constexpr int T = 1024;
    constexpr int H = 20;
    const int b    = blockIdx.x;
    const int lane = threadIdx.x;

    __shared__ float lds[128];   // 0..63: y ring; 64..127: junk sink

    // ---- per-lane constants ----
    float w[H];
    float wih_full = 0.f, bihv = 0.f, cbias = 0.f, wih_rz = 0.f;
    if (lane < 60) {
        const float sc = (lane < 40) ? LOG2E : 2.0f * LOG2E;
        #pragma unroll
        for (int k = 0; k < H; ++k) w[k] = Whh[lane * H + k] * sc;
        wih_full = Wih[lane];
        bihv     = Bih[lane];
        if (lane < 40) {               // r,z: fold b_ih+b_hh and x-weight into dot
            cbias  = (Bih[lane] + Bhh[lane]) * sc;
            wih_rz = wih_full * sc;
        } else {                        // n: b_hh into dot; gi gets 2*log2e scale
            cbias     = Bhh[lane] * sc;
            wih_full *= sc;
            bihv     *= sc;
        }
    } else if (lane == 60) {
        #pragma unroll
        for (int k = 0; k < H; ++k) w[k] = Wout[k];   // unscaled
        cbias = Bout[0];
    } else {
        #pragma unroll
        for (int k = 0; k < H; ++k) w[k] = 0.f;
    }

    const bool is_n = (lane >= 40) && (lane < 60);
    const int  jn   = lane - 40;

    // state: n-lane 40+j's hcur holds h[j]; other lanes' value is never read
    float hcur  = H0[b * H + (is_n ? jn : 0)];

    const int sr = is_n ? jn          : lane;   // bpermute src: r_j on lane j
    const int sz = is_n ? (lane + -20) : lane;  // z_j on lane 20+j

    const float4* X4 = (const float4*)(X + (size_t)b * T);
    float4 xq = X4[0];

    for (int q = 0; q < T / 4; ++q) {
        float4 xn = X4[(q < T / 4 - 1) ? (q + 1) : (T / 4 - 1)];
        #pragma unroll
        for (int u = 0; u < 4; ++u) {
            const int   i = 4 * q + u;
            const float x = (u == 0) ? xq.x : (u == 1) ? xq.y
                          : (u == 2) ? xq.z : xq.w;

            // flush 64 y-values every 64 steps (i == 65, 129, ..., 961)
            if (u == 1 && (q & 15) == 0 && q > 0) {
                Y[(size_t)b * T + (4 * q - 64) + lane] = lds[lane];
            }

            // broadcast h into SGPRs
            float hs[H];
            #pragma unroll
            for (int k = 0; k < H; ++k) hs[k] = lane_bcast(hcur, 40 + k);

            // shared pre-activation dot (two chains for ILP)
            float acc  = fmaf(x, wih_rz, cbias);
            float gi   = fmaf(x, wih_full, bihv);
            float acc2 = 0.f;
            #pragma unroll
            for (int k = 0; k < 10; ++k)  acc  = fmaf(hs[k], w[k], acc);
            #pragma unroll
            for (int k = 10; k < 20; ++k) acc2 = fmaf(hs[k], w[k], acc2);
            acc += acc2;

            // sigmoid on r,z lanes (weights pre-scaled: exp2 direct)
            float s = fast_rcp(1.f + fast_exp2(-acc));

            // transport r_j, z_j to n-lane 40+j (two overlapping bpermutes)
            float rj = __shfl(s, sr, 64);
            float zj = __shfl(s, sz, 64);

            // n = tanh(.): pre-activations already scaled by 2*log2e
            float npre = fmaf(rj, acc, gi);
            float nval = 1.f - 2.f * fast_rcp(1.f + fast_exp2(npre));
            float hnew = fmaf(zj, hcur - nval, nval);
            hcur = hnew;                     // only n-lanes' value is ever read

            // y ring: lane 60's acc == y_{i-1}; others write junk slots
            const int   waddr = (lane == 60) ? ((i + 63) & 63) : (64 + lane);
            const float wval  = (lane == 60) ? acc : 0.f;
            lds[waddr] = wval;
        }
        xq = xn;
    }

    // tail: y_{T-1} = W_out . h_T + b_out
    {
        float hs[H];
        #pragma unroll
        for (int k = 0; k < H; ++k) hs[k] = lane_bcast(hcur, 40 + k);
        float acc  = cbias;
        float acc2 = 0.f;
        #pragma unroll
        for (int k = 0; k < 10; ++k)  acc  = fmaf(hs[k], w[k], acc);
        #pragma unroll
        for (int k = 10; k < 20; ++k) acc2 = fmaf(hs[k], w[k], acc2);
        acc += acc2;
        const int   waddr = (lane == 60) ? 63 : (64 + lane);
        const float wval  = (lane == 60) ? acc : 0.f;
        lds[waddr] = wval;
        Y[(size_t)b * T + (T - 64) + lane] = lds[lane];
    }

    if (is_n) Hlast[b * H + jn] = hcur;
}

extern "C" void kernel_launch(void* const* d_in, const int* in_sizes, int n_in,
                              void* d_out, int out_size, void* d_ws, size_t ws_size,
                              hipStream_t stream) {
    const float* X    = (const float*)d_in[0];
    const float* H0   = (const float*)d_in[1];
    const float* Wih  = (const float*)d_in[2];
    const float* Whh  = (const float*)d_in[3];
    const float* Bih  = (const float*)d_in[4];
    const float* Bhh  = (const float*)d_in[5];
    const float* Wout = (const float*)d_in[6];
    const float* Bout = (const float*)d_in[7];

    constexpr int B = 2048, T = 1024, H = 20;
    float* Y     = (float*)d_out;            // [1, B*T, 1] flattened
    float* Hlast = Y + (size_t)B * T;        // [1, B, H]

    gru_fused<<<dim3(B), dim3(64), 0, stream>>>(X, H0, Wih, Whh, Bih, Bhh,
                                                Wout, Bout, Y, Hlast);
}